// Round 15
// baseline (168.204 us; speedup 1.0000x reference)
//
#include <hip/hip_runtime.h>
#include <hip/hip_bf16.h>

// RBF-KAN as one fused bf16 MFMA GEMM:
//   out[b,o] = sum_k A[b,k] * W[k,o] + bias[o]
//   k = ic*416 + slot*32 + ii, i = ic*32+ii   (BK=32: 208 K-steps, 16 chunks x 13 slots)
//   slot==0: A = x[b,i];  slot>=1: A = basis(x[b,i], g=slot-1)
// basis recurrence with u = x*1.375 + 5.5:
//   bb_0 = exp(-u^2/2); bb_{g+1} = bb_g*ff_g; ff_0 = exp(u-0.5); ff_{g+1} = ff_g*e^-1
//
// Round 15: PRODUCER/CONSUMER WAVE SPECIALIZATION. 8 waves (512 thr, 1 blk/CU):
// waves 0-3 producers (SIMDs 0-3), waves 4-7 consumers (SIMDs 0-3) -> 1P+1C
// per SIMD. Consumers: 128x64 tile each (acc[4][2]=128 -> AGPR), A from 4-deep
// LDS ring, B direct-global single reg set reloaded for t+1 at step bottom
// (unique cols, 32KB L2/step). Producers: all A-gen (16 vals/lane, bb/ff 32V),
// emit ring 2 steps ahead; VALU+exp2+x-latency hidden under consumer MFMA.
// lgkm-only barrier every 2 steps. Step time -> max(P,C) instead of sum.

#define N_DIM 512
#define I_DIM 512
#define KTOT  6656
#define NSTEP 208      // 208 K-steps of 32 = 16 chunks x 13 slots

typedef short short8 __attribute__((ext_vector_type(8)));
typedef float f32x16 __attribute__((ext_vector_type(16)));
typedef unsigned int u32x4 __attribute__((ext_vector_type(4)));

#define CVTPK(dst, lo, hi) \
  asm("v_cvt_pk_bf16_f32 %0, %1, %2" : "=v"(dst) : "v"(lo), "v"(hi))

__device__ __forceinline__ unsigned short f2bf(float f) {
  union { float f; unsigned int u; } c; c.f = f;
  unsigned int r = (c.u + 0x7FFFu + ((c.u >> 16) & 1)) >> 16;  // RNE, finite only
  return (unsigned short)r;
}

// ---------------- prep: repack coeff + base_w into bf16 Wb2[g][o][e] ----------------
// g = k >> 3 (16B k-granule, 0..831), e = k & 7; k = ic*416 + slot*32 + ii.
__global__ __launch_bounds__(256) void prep_w(const float* __restrict__ coeff,
                                              const float* __restrict__ base_w,
                                              unsigned short* __restrict__ Wb2) {
  int t = blockIdx.x * 256 + threadIdx.x;   // 851968 threads, 4 shorts each
  int e0 = (t & 1) * 4;
  int go = t >> 1;                          // g*512 + o
  int o  = go & 511;
  int g  = go >> 9;                         // 0..831
  int k4 = g * 8 + e0;
  int ic = k4 / 416;                        // 0..15
  int rem = k4 - ic * 416;
  int slot = rem >> 5;                      // 0..12
  int ii = rem & 31;
  int i = ic * 32 + ii;
  float v0, v1, v2, v3;
  if (slot == 0) {
    const float4 bw = *(const float4*)(base_w + (size_t)o * I_DIM + i);
    v0 = bw.x; v1 = bw.y; v2 = bw.z; v3 = bw.w;
  } else {
    int gg = slot - 1;
    const float* cp = coeff + (size_t)i * (N_DIM * 12) + o * 12 + gg;
    v0 = cp[0]; v1 = cp[6144]; v2 = cp[2 * 6144]; v3 = cp[3 * 6144];
  }
  ushort4 s;
  s.x = f2bf(v0); s.y = f2bf(v1); s.z = f2bf(v2); s.w = f2bf(v3);
  *(ushort4*)(Wb2 + (size_t)go * 8 + e0) = s;
}

// ---------------- main fused GEMM ----------------
__global__ __launch_bounds__(512, 2) void kan_gemm(const float* __restrict__ x,
                                                   const unsigned short* __restrict__ Wb2,
                                                   const float* __restrict__ bias,
                                                   float* __restrict__ out) {
  // A ring, 4 deep: [4][kg 4][row 128][8 bf16] = 32 KB (slot = t%4, 8 KB each)
  __shared__ unsigned short Asw[4 * 4 * 128 * 8];

  const int tid  = threadIdx.x;
  const int lane = tid & 63;
  const int wid  = tid >> 6;                  // 0-3 producers, 4-7 consumers
  const int l31  = lane & 31, hl = lane >> 5;
  const bool isCons = (wid >= 4);

  // XCD decode: XCDs 0-3 -> cb=0, XCDs 4-7 -> cb=1 (W col-panel per L2)
  const int bid = blockIdx.x;                 // grid 256
  const int xcd = bid & 7, jj = bid >> 3;     // jj 0..31
  const int cb  = xcd >> 2;
  const int rb  = jj * 4 + (xcd & 3);         // 0..127
  const int M0  = rb * 128;
  const int N0  = cb * 256;

  const char* Wb = (const char*)Wb2;

  // ================= producer state =================
  const int pid  = (wid & 3) * 64 + lane;     // 0..255
  const int prow = pid & 127;
  const int pkh  = pid >> 7;                  // k-half: k in [16*pkh, 16*pkh+16)
  const float* xrow = x + (size_t)(M0 + prow) * I_DIM + pkh * 16;
  const int paoff0 = ((pkh * 2) * 128 + prow) * 16;       // bytes within ring slot
  const int paoff1 = ((pkh * 2 + 1) * 128 + prow) * 16;
  float bb[16], ff[16];
  int eslot = 0, echunk = 0;

  // emit one K-step's A slice into ring slot pDst
  auto emitP = [&](char* pDst) {
    unsigned int w[8];
    if (eslot == 0) {                         // A = x, init basis recurrence
      const float* xp = xrow + echunk * 32;
      float4 p0 = *(const float4*)(xp);
      float4 p1 = *(const float4*)(xp + 4);
      float4 p2 = *(const float4*)(xp + 8);
      float4 p3 = *(const float4*)(xp + 12);
      float f[16] = {p0.x,p0.y,p0.z,p0.w, p1.x,p1.y,p1.z,p1.w,
                     p2.x,p2.y,p2.z,p2.w, p3.x,p3.y,p3.z,p3.w};
#pragma unroll
      for (int j = 0; j < 8; ++j) CVTPK(w[j], f[2*j], f[2*j+1]);
      *(u32x4*)(pDst + paoff0) = (u32x4){w[0], w[1], w[2], w[3]};
      *(u32x4*)(pDst + paoff1) = (u32x4){w[4], w[5], w[6], w[7]};
#pragma unroll
      for (int j = 0; j < 16; ++j) {
        float u = fmaf(f[j], 1.375f, 5.5f);
        bb[j] = exp2f(-0.72134752044448170f * u * u);                         // exp(-u^2/2)
        ff[j] = exp2f(fmaf(u, 1.44269504088896340f, -0.72134752044448170f)); // exp(u-1/2)
      }
    } else {                                  // A = basis, advance recurrence
#pragma unroll
      for (int j = 0; j < 8; ++j) CVTPK(w[j], bb[2*j], bb[2*j+1]);
      *(u32x4*)(pDst + paoff0) = (u32x4){w[0], w[1], w[2], w[3]};
      *(u32x4*)(pDst + paoff1) = (u32x4){w[4], w[5], w[6], w[7]};
#pragma unroll
      for (int j = 0; j < 16; ++j) {
        bb[j] *= ff[j];
        ff[j] *= 0.36787944117144233f;        // e^-1
      }
    }
    if (eslot == 12) { eslot = 0; ++echunk; } else { ++eslot; }
  };

  // ================= consumer state =================
  const int cw = (wid & 3);                   // consumer col group 0..3
  int boff[2][2];                             // byte offsets within 32KB step block
#pragma unroll
  for (int s = 0; s < 2; ++s)
#pragma unroll
    for (int fo = 0; fo < 2; ++fo)
      boff[s][fo] = (((s * 2 + hl) * 512) + N0 + cw * 64 + fo * 32 + l31) * 16;
  const int aBase = hl * 2048 + l31 * 16;     // + s*4096 + fb*512

  f32x16 acc[4][2];
#pragma unroll
  for (int i = 0; i < 4; ++i)
#pragma unroll
    for (int j = 0; j < 2; ++j)
#pragma unroll
      for (int r = 0; r < 16; ++r) acc[i][j][r] = 0.f;

  short8 bv[2][2];                            // single B set, reloaded per step

  auto loadBnext = [&](int tt) {              // load B for step tt
    const char* WbT = Wb + (size_t)tt * 32768;
#pragma unroll
    for (int s = 0; s < 2; ++s) {
      bv[s][0] = *(const short8*)(WbT + boff[s][0]);
      bv[s][1] = *(const short8*)(WbT + boff[s][1]);
    }
  };

  auto consStep = [&](int tt, bool loadNext) {
    const char* pA = (const char*)Asw + ((tt & 3) << 13);
#pragma unroll
    for (int s = 0; s < 2; ++s) {
      short8 av[4];
#pragma unroll
      for (int fb = 0; fb < 4; ++fb)
        av[fb] = *(const short8*)(pA + s * 4096 + fb * 512 + aBase);
#pragma unroll
      for (int fb = 0; fb < 4; ++fb) {
        acc[fb][0] = __builtin_amdgcn_mfma_f32_32x32x16_bf16(av[fb], bv[s][0], acc[fb][0], 0, 0, 0);
        acc[fb][1] = __builtin_amdgcn_mfma_f32_32x32x16_bf16(av[fb], bv[s][1], acc[fb][1], 0, 0, 0);
      }
    }
    if (loadNext) loadBnext(tt + 1);
  };

  // ================= prologue =================
  if (isCons) {
    loadBnext(0);                             // B(0)
  } else {
    emitP((char*)Asw);                        // A(0) -> slot 0
    emitP((char*)Asw + 8192);                 // A(1) -> slot 1
  }
  asm volatile("s_waitcnt lgkmcnt(0)" ::: "memory");
  __builtin_amdgcn_s_barrier();

  // ============ main loop: 2 steps per barrier window (103 windows) ============
#pragma unroll 1
  for (int t = 0; t < 206; t += 2) {
    if (isCons) {
      consStep(t, true);
      consStep(t + 1, true);
    } else {
      emitP((char*)Asw + (((t + 2) & 3) << 13));
      emitP((char*)Asw + (((t + 3) & 3) << 13));
    }
    asm volatile("s_waitcnt lgkmcnt(0)" ::: "memory");
    __builtin_amdgcn_s_barrier();
  }
  // final window: steps 206, 207 (no emits, no trailing load, no barrier)
  if (isCons) {
    consStep(206, true);
    consStep(207, false);

    // ---- epilogue: D col(o)=lane&31, row(b)=(r&3)+8*(r>>2)+4*hl ----
    float bvv[2];
#pragma unroll
    for (int fo = 0; fo < 2; ++fo) bvv[fo] = bias[N0 + cw * 64 + fo * 32 + l31];
    const int rbase = 4 * hl;
#pragma unroll
    for (int fb = 0; fb < 4; ++fb) {
#pragma unroll
      for (int fo = 0; fo < 2; ++fo) {
        const size_t cix = (size_t)(N0 + cw * 64 + fo * 32 + l31);
#pragma unroll
        for (int r = 0; r < 16; ++r) {
          int row = M0 + fb * 32 + (r & 3) + 8 * (r >> 2) + rbase;
          out[(size_t)row * N_DIM + cix] = acc[fb][fo][r] + bvv[fo];
        }
      }
    }
  }
}

extern "C" void kernel_launch(void* const* d_in, const int* in_sizes, int n_in,
                              void* d_out, int out_size, void* d_ws, size_t ws_size,
                              hipStream_t stream) {
  const float* x      = (const float*)d_in[0];
  const float* coeff  = (const float*)d_in[1];
  const float* base_w = (const float*)d_in[2];
  const float* base_b = (const float*)d_in[3];
  // d_in[4] (centers) is implied by u = x*1.375 + 5.5 (exact)
  unsigned short* Wb2 = (unsigned short*)d_ws;   // needs 6,815,744 B

  prep_w<<<3328, 256, 0, stream>>>(coeff, base_w, Wb2);
  kan_gemm<<<256, 512, 0, stream>>>(x, Wb2, base_b, (float*)d_out);
}

// Round 17
// 132.207 us; speedup vs baseline: 1.2723x; 1.2723x over previous
//
#include <hip/hip_runtime.h>
#include <hip/hip_bf16.h>

// RBF-KAN as one fused bf16 MFMA GEMM:
//   out[b,o] = sum_k A[b,k] * W[k,o] + bias[o]
//   k = ic*416 + slot*32 + ii, i = ic*32+ii   (BK=32: 208 K-steps, 16 chunks x 13 slots)
//   slot==0: A = x[b,i];  slot>=1: A = basis(x[b,i], g=slot-1)
// basis recurrence with u = x*1.375 + 5.5:
//   bb_0 = exp(-u^2/2); bb_{g+1} = bb_g*ff_g; ff_0 = exp(u-0.5); ff_{g+1} = ff_g*e^-1
//
// Round 17: r16 with the diagnosed correctness fix: B-set reload runs for ALL
// main-loop windows (t<=204 => tt+2<=207 always valid). r16's `t<204` guard
// left steps 206/207 consuming stale B(204)/B(205) -> absmax 0.44.
// Structure: producers (waves 0-3) generate A into a 4-deep LDS ring 2 steps
// ahead; consumers (waves 4-7) own 128x64 tiles, hold TWO named B register
// sets each reloaded a full 2-step window before consumption; lgkm-only
// barrier every 2 steps; B loads stay in flight across barriers.

#define N_DIM 512
#define I_DIM 512
#define KTOT  6656
#define NSTEP 208      // 208 K-steps of 32 = 16 chunks x 13 slots

typedef short short8 __attribute__((ext_vector_type(8)));
typedef float f32x16 __attribute__((ext_vector_type(16)));
typedef unsigned int u32x4 __attribute__((ext_vector_type(4)));

#define CVTPK(dst, lo, hi) \
  asm("v_cvt_pk_bf16_f32 %0, %1, %2" : "=v"(dst) : "v"(lo), "v"(hi))

__device__ __forceinline__ unsigned short f2bf(float f) {
  union { float f; unsigned int u; } c; c.f = f;
  unsigned int r = (c.u + 0x7FFFu + ((c.u >> 16) & 1)) >> 16;  // RNE, finite only
  return (unsigned short)r;
}

// ---------------- prep: repack coeff + base_w into bf16 Wb2[g][o][e] ----------------
// g = k >> 3 (16B k-granule, 0..831), e = k & 7; k = ic*416 + slot*32 + ii.
__global__ __launch_bounds__(256) void prep_w(const float* __restrict__ coeff,
                                              const float* __restrict__ base_w,
                                              unsigned short* __restrict__ Wb2) {
  int t = blockIdx.x * 256 + threadIdx.x;   // 851968 threads, 4 shorts each
  int e0 = (t & 1) * 4;
  int go = t >> 1;                          // g*512 + o
  int o  = go & 511;
  int g  = go >> 9;                         // 0..831
  int k4 = g * 8 + e0;
  int ic = k4 / 416;                        // 0..15
  int rem = k4 - ic * 416;
  int slot = rem >> 5;                      // 0..12
  int ii = rem & 31;
  int i = ic * 32 + ii;
  float v0, v1, v2, v3;
  if (slot == 0) {
    const float4 bw = *(const float4*)(base_w + (size_t)o * I_DIM + i);
    v0 = bw.x; v1 = bw.y; v2 = bw.z; v3 = bw.w;
  } else {
    int gg = slot - 1;
    const float* cp = coeff + (size_t)i * (N_DIM * 12) + o * 12 + gg;
    v0 = cp[0]; v1 = cp[6144]; v2 = cp[2 * 6144]; v3 = cp[3 * 6144];
  }
  ushort4 s;
  s.x = f2bf(v0); s.y = f2bf(v1); s.z = f2bf(v2); s.w = f2bf(v3);
  *(ushort4*)(Wb2 + (size_t)go * 8 + e0) = s;
}

// ---------------- main fused GEMM ----------------
__global__ __launch_bounds__(512, 2) void kan_gemm(const float* __restrict__ x,
                                                   const unsigned short* __restrict__ Wb2,
                                                   const float* __restrict__ bias,
                                                   float* __restrict__ out) {
  // A ring, 4 deep: [4][kg 4][row 128][8 bf16] = 32 KB (slot = t%4, 8 KB each)
  __shared__ unsigned short Asw[4 * 4 * 128 * 8];

  const int tid  = threadIdx.x;
  const int lane = tid & 63;
  const int wid  = tid >> 6;                  // 0-3 producers, 4-7 consumers
  const int l31  = lane & 31, hl = lane >> 5;
  const bool isCons = (wid >= 4);

  // XCD decode: XCDs 0-3 -> cb=0, XCDs 4-7 -> cb=1 (W col-panel per L2)
  const int bid = blockIdx.x;                 // grid 256
  const int xcd = bid & 7, jj = bid >> 3;     // jj 0..31
  const int cb  = xcd >> 2;
  const int rb  = jj * 4 + (xcd & 3);         // 0..127
  const int M0  = rb * 128;
  const int N0  = cb * 256;

  const char* Wb = (const char*)Wb2;

  // ================= producer state =================
  const int pid  = (wid & 3) * 64 + lane;     // 0..255
  const int prow = pid & 127;
  const int pkh  = pid >> 7;                  // k-half: k in [16*pkh, 16*pkh+16)
  const float* xrow = x + (size_t)(M0 + prow) * I_DIM + pkh * 16;
  const int paoff0 = ((pkh * 2) * 128 + prow) * 16;       // bytes within ring slot
  const int paoff1 = ((pkh * 2 + 1) * 128 + prow) * 16;
  float bb[16], ff[16];
  int eslot = 0, echunk = 0;

  auto emitP = [&](char* pDst) {
    unsigned int w[8];
    if (eslot == 0) {                         // A = x, init basis recurrence
      const float* xp = xrow + echunk * 32;
      float4 p0 = *(const float4*)(xp);
      float4 p1 = *(const float4*)(xp + 4);
      float4 p2 = *(const float4*)(xp + 8);
      float4 p3 = *(const float4*)(xp + 12);
      float f[16] = {p0.x,p0.y,p0.z,p0.w, p1.x,p1.y,p1.z,p1.w,
                     p2.x,p2.y,p2.z,p2.w, p3.x,p3.y,p3.z,p3.w};
#pragma unroll
      for (int j = 0; j < 8; ++j) CVTPK(w[j], f[2*j], f[2*j+1]);
      *(u32x4*)(pDst + paoff0) = (u32x4){w[0], w[1], w[2], w[3]};
      *(u32x4*)(pDst + paoff1) = (u32x4){w[4], w[5], w[6], w[7]};
#pragma unroll
      for (int j = 0; j < 16; ++j) {
        float u = fmaf(f[j], 1.375f, 5.5f);
        bb[j] = exp2f(-0.72134752044448170f * u * u);                         // exp(-u^2/2)
        ff[j] = exp2f(fmaf(u, 1.44269504088896340f, -0.72134752044448170f)); // exp(u-1/2)
      }
    } else {                                  // A = basis, advance recurrence
#pragma unroll
      for (int j = 0; j < 8; ++j) CVTPK(w[j], bb[2*j], bb[2*j+1]);
      *(u32x4*)(pDst + paoff0) = (u32x4){w[0], w[1], w[2], w[3]};
      *(u32x4*)(pDst + paoff1) = (u32x4){w[4], w[5], w[6], w[7]};
#pragma unroll
      for (int j = 0; j < 16; ++j) {
        bb[j] *= ff[j];
        ff[j] *= 0.36787944117144233f;        // e^-1
      }
    }
    if (eslot == 12) { eslot = 0; ++echunk; } else { ++eslot; }
  };

  // ================= consumer state =================
  const int cw = (wid & 3);                   // consumer col group 0..3
  int boff[2][2];                             // byte offsets within 32KB step block
#pragma unroll
  for (int s = 0; s < 2; ++s)
#pragma unroll
    for (int fo = 0; fo < 2; ++fo)
      boff[s][fo] = (((s * 2 + hl) * 512) + N0 + cw * 64 + fo * 32 + l31) * 16;
  const int aBase = hl * 2048 + l31 * 16;     // + s*4096 + fb*512

  f32x16 acc[4][2];
#pragma unroll
  for (int i = 0; i < 4; ++i)
#pragma unroll
    for (int j = 0; j < 2; ++j)
#pragma unroll
      for (int r = 0; r < 16; ++r) acc[i][j][r] = 0.f;

  short8 bvA[2][2], bvB[2][2];                // TWO named B sets (2-step pipeline)

  auto loadBinto = [&](short8 (&bv)[2][2], int tt) {
    const char* WbT = Wb + (size_t)tt * 32768;
#pragma unroll
    for (int s = 0; s < 2; ++s) {
      bv[s][0] = *(const short8*)(WbT + boff[s][0]);
      bv[s][1] = *(const short8*)(WbT + boff[s][1]);
    }
  };

  // consume step tt with B set bv (loaded a full window ago); then reload the
  // SAME set with B(tt+2) so it has ~2 steps + barrier to land.
  auto consStep = [&](int tt, short8 (&bv)[2][2], bool reload) {
    const char* pA = (const char*)Asw + ((tt & 3) << 13);
    short8 av[2][4];
#pragma unroll
    for (int s = 0; s < 2; ++s)
#pragma unroll
      for (int fb = 0; fb < 4; ++fb)
        av[s][fb] = *(const short8*)(pA + s * 4096 + fb * 512 + aBase);
#pragma unroll
    for (int s = 0; s < 2; ++s)
#pragma unroll
      for (int fb = 0; fb < 4; ++fb) {
        acc[fb][0] = __builtin_amdgcn_mfma_f32_32x32x16_bf16(av[s][fb], bv[s][0], acc[fb][0], 0, 0, 0);
        acc[fb][1] = __builtin_amdgcn_mfma_f32_32x32x16_bf16(av[s][fb], bv[s][1], acc[fb][1], 0, 0, 0);
      }
    if (reload) loadBinto(bv, tt + 2);
  };

  // ================= prologue =================
  if (isCons) {
    loadBinto(bvA, 0);                        // B(0)
    loadBinto(bvB, 1);                        // B(1)
  } else {
    emitP((char*)Asw);                        // A(0) -> slot 0
    emitP((char*)Asw + 8192);                 // A(1) -> slot 1
  }
  asm volatile("s_waitcnt lgkmcnt(0)" ::: "memory");
  __builtin_amdgcn_s_barrier();

  // ============ main loop: 2 steps per barrier window (103 windows) ============
  // For every window t<=204: tt+2 <= 206 and tt+3 <= 207 -> ALWAYS reload.
#pragma unroll 1
  for (int t = 0; t < 206; t += 2) {
    if (isCons) {
      consStep(t,     bvA, true);             // reload bvA = B(t+2), t+2 <= 206
      consStep(t + 1, bvB, true);             // reload bvB = B(t+3), t+3 <= 207
    } else {
      emitP((char*)Asw + (((t + 2) & 3) << 13));
      emitP((char*)Asw + (((t + 3) & 3) << 13));
    }
    asm volatile("s_waitcnt lgkmcnt(0)" ::: "memory");
    __builtin_amdgcn_s_barrier();
  }
  // final window: steps 206, 207 (B already resident; no emits, no barrier)
  if (isCons) {
    consStep(206, bvA, false);
    consStep(207, bvB, false);

    // ---- epilogue: D col(o)=lane&31, row(b)=(r&3)+8*(r>>2)+4*hl ----
    float bvv[2];
#pragma unroll
    for (int fo = 0; fo < 2; ++fo) bvv[fo] = bias[N0 + cw * 64 + fo * 32 + l31];
    const int rbase = 4 * hl;
#pragma unroll
    for (int fb = 0; fb < 4; ++fb) {
#pragma unroll
      for (int fo = 0; fo < 2; ++fo) {
        const size_t cix = (size_t)(N0 + cw * 64 + fo * 32 + l31);
#pragma unroll
        for (int r = 0; r < 16; ++r) {
          int row = M0 + fb * 32 + (r & 3) + 8 * (r >> 2) + rbase;
          out[(size_t)row * N_DIM + cix] = acc[fb][fo][r] + bvv[fo];
        }
      }
    }
  }
}

extern "C" void kernel_launch(void* const* d_in, const int* in_sizes, int n_in,
                              void* d_out, int out_size, void* d_ws, size_t ws_size,
                              hipStream_t stream) {
  const float* x      = (const float*)d_in[0];
  const float* coeff  = (const float*)d_in[1];
  const float* base_w = (const float*)d_in[2];
  const float* base_b = (const float*)d_in[3];
  // d_in[4] (centers) is implied by u = x*1.375 + 5.5 (exact)
  unsigned short* Wb2 = (unsigned short*)d_ws;   // needs 6,815,744 B

  prep_w<<<3328, 256, 0, stream>>>(coeff, base_w, Wb2);
  kan_gemm<<<256, 512, 0, stream>>>(x, Wb2, base_b, (float*)d_out);
}